// Round 22
// baseline (160.828 us; speedup 1.0000x reference)
//
#include <hip/hip_runtime.h>
#include <hip/hip_bf16.h>

#define N_TOK 32768
#define DIM   512
#define NE    2048

#define IDX_OFF  (N_TOK * DIM)
#define LOSS_OFF (IDX_OFF + N_TOK)
#define PERP_OFF (LOSS_OFF + 1)

#define KB(x) ((size_t)(x) << 10)
#define EPS 4e-4f
#define EPS_SEL 1e-3f   // EPS + 2*bf16-quantization bound on stored group mins

// Row-interleaved d_out scratch: token t's 2048B z_q slot holds
//   [0,512)    gmv[t]: 128 u32 (bf16 groupmin << 16 | mask16)
//   [512,1536) zbf[t]: 512 bf16 (z row, bf16)
// gemm reads zbf bytes + writes gmv bytes of the same rows (disjoint);
// select reads own-row gmv then overwrites own row with z_q. Race-free.

typedef __attribute__((ext_vector_type(8))) short bf16x8;
typedef __attribute__((ext_vector_type(4))) float f32x4;

__device__ inline unsigned short f2bf(float f) {
  unsigned int x = __float_as_uint(f);
  x = x + 0x7fffu + ((x >> 16) & 1u);
  return (unsigned short)(x >> 16);
}
__device__ inline float bfround(float f) {
  return __uint_as_float((unsigned int)f2bf(f) << 16);
}

// np.sum(x*x) exact replication (validated round 4 — sum chain untouched)
// + fused bf16 conversion. z's bf16 copy goes to row-interleaved slots.
__global__ __launch_bounds__(256) void npsum_cvt_all(
    const float* __restrict__ z, const float* __restrict__ e,
    float* __restrict__ zsum, float* __restrict__ esum,
    float* __restrict__ out, unsigned short* __restrict__ ebf,
    int* __restrict__ counts) {
#pragma clang fp contract(off)
  const int bz = blockIdx.x;
  if (bz < 8) counts[bz * 256 + threadIdx.x] = 0;
  const bool isz = bz < (N_TOK / 16);
  const int blk = isz ? bz : bz - (N_TOK / 16);
  const float* x = isz ? z : e;
  float* outs = isz ? zsum : esum;

  int wave = threadIdx.x >> 6;
  int lane = threadIdx.x & 63;
  int grp = lane >> 4, l = lane & 15;
  int row = blk * 16 + wave * 4 + grp;
  {
    const float* a = x + (size_t)row * DIM;
    float L[4];
    #pragma unroll
    for (int b = 0; b < 4; ++b) {
      const float* p = a + b * 128 + l;
      float q[8];
      #pragma unroll
      for (int j = 0; j < 8; ++j) {
        float t = p[16 * j];
        float s = t * t;
        asm volatile("" : "+v"(s));
        q[j] = s;
      }
      float v = ((q[0] + q[1]) + (q[2] + q[3])) + ((q[4] + q[5]) + (q[6] + q[7]));
      v += __shfl_xor(v, 8);
      v += __shfl_xor(v, 4);
      v += __shfl_xor(v, 2);
      v += __shfl_xor(v, 1);
      L[b] = v;
    }
    if (l == 0) outs[row] = (L[0] + L[1]) + (L[2] + L[3]);
  }
  const float* blkp = x + (size_t)blk * 16 * DIM;
  #pragma unroll
  for (int u = 0; u < 4; ++u) {
    size_t off = (size_t)(u * 256 + threadIdx.x) * 8;
    float4 a2 = *(const float4*)(blkp + off);
    float4 b2 = *(const float4*)(blkp + off + 4);
    unsigned short h[8] = {f2bf(a2.x), f2bf(a2.y), f2bf(a2.z), f2bf(a2.w),
                           f2bf(b2.x), f2bf(b2.y), f2bf(b2.z), f2bf(b2.w)};
    if (isz) {
      int r = (int)(off >> 9), c = (int)(off & 511);
      unsigned short* rp = (unsigned short*)((char*)out +
          (size_t)(blk * 16 + r) * 2048 + 512);
      *(uint4*)(rp + c) = *(uint4*)h;
    } else {
      *(uint4*)(ebf + off + (size_t)blk * 16 * DIM) = *(uint4*)h;
    }
  }
}

// Stage one 128x64-bf16 half-tile (16KB) via global_load_lds width 16.
// rstride: row stride in u16 units (A: 512 contiguous; B: 1024 interleaved).
__device__ inline void stage_half(const unsigned short* __restrict__ gsrc,
                                  unsigned short* lds, int w, int l, int rstride) {
  const int swz_col = ((l & 7) ^ (l >> 3)) * 8;
  const int rsub = l >> 3;
  #pragma unroll
  for (int s4 = 0; s4 < 2; ++s4) {
    int s = w * 2 + s4;
    const unsigned short* g = gsrc + (size_t)(s * 8 + rsub) * rstride + swz_col;
    __builtin_amdgcn_global_load_lds(
        (const __attribute__((address_space(1))) unsigned int*)g,
        (__attribute__((address_space(3))) unsigned int*)(lds + s * 512),
        16, 0, 0);
  }
}

#define BAR()   asm volatile("s_barrier" ::: "memory")
#define VMCNT4  asm volatile("s_waitcnt vmcnt(4)" ::: "memory")
#define VMCNT0  asm volatile("s_waitcnt vmcnt(0)" ::: "memory")

// 8-phase MFMA GEMM — R15 structure, register epilogue (validated R20/21).
// B (z) read from row-interleaved zbf (stride 1024 u16); gmv written to
// token rows' first 512B (disjoint from zbf bytes — race-free).
__global__ __launch_bounds__(512, 2) void gemm_groupmin(
    const unsigned short* __restrict__ ebf, float* __restrict__ out,
    const float* __restrict__ esum) {
  extern __shared__ unsigned short smem[];
  unsigned short* As = smem;
  unsigned short* Bs = smem + 32768;

  const int tid = threadIdx.x;
  const int tb = blockIdx.x;   // token block (128) — XCD-swizzled grid
  const int cb = blockIdx.y;   // code block (8)
  const int w = tid >> 6, l = tid & 63;
  const int lr = l & 15, lk = l >> 4;
  const int wrow = (w >> 2) * 128;
  const int wcol = (w & 3) * 64;

  f32x4 acc[8][4];
  #pragma unroll
  for (int i = 0; i < 8; ++i)
    #pragma unroll
    for (int j = 0; j < 4; ++j) acc[i][j] = (f32x4)(0.f);

  bf16x8 aR[8], bA[4], bB[4];

  const unsigned short* Ag = ebf + (size_t)(cb * 256) * DIM;
  const unsigned short* Bg = (const unsigned short*)((const char*)out +
      (size_t)(tb * 256) * 2048 + 512);

#define LOADA(slot, qm) do { \
  _Pragma("unroll") for (int i2 = 0; i2 < 4; ++i2) { \
    int R = wrow + (qm)*64 + i2*16 + lr; \
    int rbase = ((slot)*2 + (R>>7))*8192 + (R&127)*64; \
    aR[i2*2+0] = *(const bf16x8*)&As[rbase + (((lk    ) ^ (R&7))*8)]; \
    aR[i2*2+1] = *(const bf16x8*)&As[rbase + (((4 + lk) ^ (R&7))*8)]; \
  } } while (0)

#define LOADB(dst, slot, qn) do { \
  _Pragma("unroll") for (int j = 0; j < 2; ++j) { \
    int C = wcol + (qn)*32 + j*16 + lr; \
    int cbase = ((slot)*2 + (C>>7))*8192 + (C&127)*64; \
    dst[j*2+0] = *(const bf16x8*)&Bs[cbase + (((lk    ) ^ (C&7))*8)]; \
    dst[j*2+1] = *(const bf16x8*)&Bs[cbase + (((4 + lk) ^ (C&7))*8)]; \
  } } while (0)

#define MFMA16(qm, qn, bX) do { \
  __builtin_amdgcn_s_setprio(1); \
  _Pragma("unroll") for (int i2 = 0; i2 < 4; ++i2) \
    _Pragma("unroll") for (int j = 0; j < 2; ++j) { \
      acc[(qm)*4+i2][(qn)*2+j] = __builtin_amdgcn_mfma_f32_16x16x32_bf16( \
          aR[i2*2+0], bX[j*2+0], acc[(qm)*4+i2][(qn)*2+j], 0, 0, 0); \
      acc[(qm)*4+i2][(qn)*2+j] = __builtin_amdgcn_mfma_f32_16x16x32_bf16( \
          aR[i2*2+1], bX[j*2+1], acc[(qm)*4+i2][(qn)*2+j], 0, 0, 0); \
    } \
  __builtin_amdgcn_s_setprio(0); \
} while (0)

  stage_half(Bg,                  Bs,            w, l, 1024);
  stage_half(Bg + 128 * 1024,     Bs + 8192,     w, l, 1024);
  stage_half(Ag,                  As,            w, l, 512);
  stage_half(Ag + 128 * DIM,      As + 8192,     w, l, 512);
  stage_half(Bg + 64,             Bs + 2 * 8192, w, l, 1024);
  stage_half(Bg + 128 * 1024 + 64, Bs + 3 * 8192, w, l, 1024);
  VMCNT4;
  BAR();

  #pragma unroll
  for (int i = 0; i < 4; ++i) {
    const int t1k = (2 * i + 1) * 64;
    const int u0k = (2 * i + 2) * 64;
    const int u1k = (2 * i + 3) * 64;
    LOADA(0, 0); LOADB(bA, 0, 0); LOADB(bB, 0, 1);
    stage_half(Ag + t1k, As + 2 * 8192, w, l, 512);
    BAR(); MFMA16(0, 0, bA);
    stage_half(Ag + 128 * DIM + t1k, As + 3 * 8192, w, l, 512);
    BAR(); MFMA16(0, 1, bB);
    LOADA(0, 1);
    if (i < 3) stage_half(Bg + u0k, Bs, w, l, 1024);
    BAR(); MFMA16(1, 0, bA);
    if (i < 3) stage_half(Bg + 128 * 1024 + u0k, Bs + 8192, w, l, 1024);
    BAR(); MFMA16(1, 1, bB);
    if (i < 3) { VMCNT4; } else { VMCNT0; }
    BAR();
    LOADA(1, 0); LOADB(bA, 1, 0); LOADB(bB, 1, 1);
    if (i < 3) stage_half(Ag + u0k, As, w, l, 512);
    BAR(); MFMA16(0, 0, bA);
    if (i < 3) stage_half(Ag + 128 * DIM + u0k, As + 8192, w, l, 512);
    BAR(); MFMA16(0, 1, bB);
    LOADA(1, 1);
    if (i < 3) stage_half(Bg + u1k, Bs + 2 * 8192, w, l, 1024);
    BAR(); MFMA16(1, 0, bA);
    if (i < 3) stage_half(Bg + 128 * 1024 + u1k, Bs + 3 * 8192, w, l, 1024);
    BAR(); MFMA16(1, 1, bB);
    if (i < 3) { VMCNT4; BAR(); }
  }

  float esr[8][4];
  #pragma unroll
  for (int i = 0; i < 8; ++i)
    #pragma unroll
    for (int q = 0; q < 4; ++q)
      esr[i][q] = esum[cb * 256 + wrow + i * 16 + lk * 4 + q];

  unsigned gmv8[4][8];
  #pragma unroll
  for (int i = 0; i < 8; ++i) {
    #pragma unroll
    for (int j = 0; j < 4; ++j) {
      float v0 = fmaf(-2.f, acc[i][j][0], esr[i][0]);
      float v1 = fmaf(-2.f, acc[i][j][1], esr[i][1]);
      float v2 = fmaf(-2.f, acc[i][j][2], esr[i][2]);
      float v3 = fmaf(-2.f, acc[i][j][3], esr[i][3]);
      float m = fminf(fminf(v0, v1), fminf(v2, v3));
      m = fminf(m, __shfl_xor(m, 16));
      m = fminf(m, __shfl_xor(m, 32));
      float gl = m + EPS;
      int mk = (((v0 <= gl) ? 1 : 0) | ((v1 <= gl) ? 2 : 0) |
                ((v2 <= gl) ? 4 : 0) | ((v3 <= gl) ? 8 : 0)) << (lk * 4);
      mk |= __shfl_xor(mk, 16);
      mk |= __shfl_xor(mk, 32);
      gmv8[j][i] = ((unsigned)f2bf(m) << 16) | (unsigned)(mk & 0xFFFF);
    }
  }
  if (lk == 0) {
    #pragma unroll
    for (int j = 0; j < 4; ++j) {
      int token = tb * 256 + wcol + j * 16 + lr;
      unsigned* gr = (unsigned*)((char*)out + (size_t)token * 2048);
      int gofs = cb * 16 + (w >> 2) * 8;
      uint4 q0 = {gmv8[j][0], gmv8[j][1], gmv8[j][2], gmv8[j][3]};
      uint4 q1 = {gmv8[j][4], gmv8[j][5], gmv8[j][6], gmv8[j][7]};
      *(uint4*)&gr[gofs] = q0;
      *(uint4*)&gr[gofs + 4] = q1;
    }
  }
#undef LOADA
#undef LOADB
#undef MFMA16
}

// One wave per token: mask-guided exact rescan (validated R18-R21) reading
// own-row gmv, then UNCONDITIONAL fused z_q write over its own row.
__global__ __launch_bounds__(256) void select_exact(
    const float* __restrict__ z, const float* __restrict__ e,
    const float* __restrict__ zsum, const float* __restrict__ esum,
    int* __restrict__ counts, float* __restrict__ out,
    float* __restrict__ lossp) {
  __shared__ float lred[4];
  const int wid = threadIdx.x >> 6;
  const int t = blockIdx.x * 4 + wid;
  const int lane = threadIdx.x & 63;
  const float* zr = z + (size_t)t * DIM;

  float4 za = *(const float4*)(zr + lane * 4);
  float4 zb = *(const float4*)(zr + 256 + lane * 4);

  const unsigned* gr = (const unsigned*)((const char*)out + (size_t)t * 2048);
  unsigned u0 = gr[lane];
  unsigned u1 = gr[64 + lane];
  float g0 = __uint_as_float(u0 & 0xFFFF0000u);
  float g1 = __uint_as_float(u1 & 0xFFFF0000u);
  float m = fminf(g0, g1);
  #pragma unroll
  for (int s = 32; s >= 1; s >>= 1) m = fminf(m, __shfl_xor(m, s));
  float lim = m + EPS_SEL;
  unsigned long long mm0 = __ballot(g0 <= lim);
  unsigned long long mm1 = __ballot(g1 <= lim);
  float zst = zsum[t];
  float bd = 3.402823466e38f; int bc = 0x7fffffff;

  #pragma unroll 1
  for (int half = 0; half < 2; ++half) {
    unsigned long long mk = half ? mm1 : mm0;
    while (mk) {
      int b = __ffsll((unsigned long long)mk) - 1;
      mk &= mk - 1;
      const int base = (half * 64 + b) * 16;
      unsigned gm = (unsigned)__shfl((int)(half ? u1 : u0), b) & 0xFFFFu;
      while (gm) {
        int ci = __ffs(gm) - 1;
        gm &= gm - 1;
        int c = base + ci;
        const float* er = e + (size_t)c * DIM;
        float4 ea = *(const float4*)(er + lane * 4);
        float4 eb = *(const float4*)(er + 256 + lane * 4);
        float p = 0.f;
        p = fmaf(za.x, ea.x, p); p = fmaf(za.y, ea.y, p);
        p = fmaf(za.z, ea.z, p); p = fmaf(za.w, ea.w, p);
        p = fmaf(zb.x, eb.x, p); p = fmaf(zb.y, eb.y, p);
        p = fmaf(zb.z, eb.z, p); p = fmaf(zb.w, eb.w, p);
        #pragma unroll
        for (int s = 1; s <= 32; s <<= 1) p += __shfl_xor(p, s);
        float d = (zst + esum[c]) - 2.f * p;
        if (d < bd) { bd = d; bc = c; }   // ascending c => first-index ties
      }
    }
  }
  // fused z_q write: own row only (gmv already consumed into registers)
  {
    const float* er = e + (size_t)(bc & (NE - 1)) * DIM;
    float4 ea = *(const float4*)(er + lane * 4);
    float4 eb = *(const float4*)(er + 256 + lane * 4);
    float* op = out + (size_t)t * DIM;
    float4 oa, ob;
    oa.x = bfround(ea.x); oa.y = bfround(ea.y);
    oa.z = bfround(ea.z); oa.w = bfround(ea.w);
    ob.x = bfround(eb.x); ob.y = bfround(eb.y);
    ob.z = bfround(eb.z); ob.w = bfround(eb.w);
    *(float4*)(op + lane * 4) = oa;
    *(float4*)(op + 256 + lane * 4) = ob;
  }
  if (lane == 0) {
    out[IDX_OFF + t] = bfround((float)bc);
    atomicAdd(&counts[bc], 1);
    lred[wid] = bd;
  }
  __syncthreads();
  if (threadIdx.x == 0)
    lossp[blockIdx.x] = (lred[0] + lred[1]) + (lred[2] + lred[3]);
}

__global__ __launch_bounds__(256) void fin_only(
    const int* __restrict__ counts, const float* __restrict__ lossp,
    float* __restrict__ out) {
  __shared__ float red[4], red2[4];
  int tid = threadIdx.x;
  float s = 0.f;
  for (int j = tid; j < NE; j += 256) {
    float p = (float)counts[j] * (1.0f / (float)N_TOK);
    s += p * logf(p + 1e-10f);
  }
  float ls = 0.f;
  for (int j = tid; j < N_TOK / 4; j += 256) ls += lossp[j];
  #pragma unroll
  for (int m = 32; m >= 1; m >>= 1) {
    s += __shfl_xor(s, m);
    ls += __shfl_xor(ls, m);
  }
  if ((tid & 63) == 0) { red[tid >> 6] = s; red2[tid >> 6] = ls; }
  __syncthreads();
  if (tid == 0) {
    float tot = red[0] + red[1] + red[2] + red[3];
    float lt = red2[0] + red2[1] + red2[2] + red2[3];
    out[PERP_OFF] = bfround(expf(-tot));
    out[LOSS_OFF] = bfround(lt * 1.25f / (float)(N_TOK * DIM));
  }
}

extern "C" void kernel_launch(void* const* d_in, const int* in_sizes, int n_in,
                              void* d_out, int out_size, void* d_ws, size_t ws_size,
                              hipStream_t stream) {
  const float* z = (const float*)d_in[0];
  const float* e = (const float*)d_in[1];
  float* out = (float*)d_out;
  char* ws = (char*)d_ws;

  float*    zsum   = (float*)(ws + KB(0));      // 128 KB
  float*    esum   = (float*)(ws + KB(128));    // 8 KB
  int*      counts = (int*)(ws + KB(136));      // 8 KB
  float*    lossp  = (float*)(ws + KB(144));    // 32 KB
  unsigned short* ebf = (unsigned short*)(ws + KB(176)); // 2 MB -> ends 2224 KB

  npsum_cvt_all<<<N_TOK / 16 + NE / 16, 256, 0, stream>>>(
      z, e, zsum, esum, out, ebf, counts);
  gemm_groupmin<<<dim3(N_TOK / 256, NE / 256), 512, 131072, stream>>>(
      ebf, out, esum);
  select_exact<<<N_TOK / 4, 256, 0, stream>>>(z, e, zsum, esum,
                                              counts, out, lossp);
  fin_only<<<1, 256, 0, stream>>>(counts, lossp, out);
}

// Round 23
// 158.272 us; speedup vs baseline: 1.0161x; 1.0161x over previous
//
#include <hip/hip_runtime.h>
#include <hip/hip_bf16.h>

#define N_TOK 32768
#define DIM   512
#define NE    2048

#define IDX_OFF  (N_TOK * DIM)
#define LOSS_OFF (IDX_OFF + N_TOK)
#define PERP_OFF (LOSS_OFF + 1)

#define KB(x) ((size_t)(x) << 10)
#define EPS 4e-4f
#define EPS_SEL 1e-3f   // EPS + 2*bf16-quantization bound on stored group mins

typedef __attribute__((ext_vector_type(8))) short bf16x8;
typedef __attribute__((ext_vector_type(4))) float f32x4;

__device__ inline unsigned short f2bf(float f) {
  unsigned int x = __float_as_uint(f);
  x = x + 0x7fffu + ((x >> 16) & 1u);
  return (unsigned short)(x >> 16);
}
__device__ inline float bfround(float f) {
  return __uint_as_float((unsigned int)f2bf(f) << 16);
}

// Combined: np.sum(x*x) exact replication (validated round 4 — sum chain
// untouched) + fused bf16 conversion for z and e. Blocks 0..7 zero counts.
__global__ __launch_bounds__(256) void npsum_cvt_all(
    const float* __restrict__ z, const float* __restrict__ e,
    float* __restrict__ zsum, float* __restrict__ esum,
    unsigned short* __restrict__ zbf, unsigned short* __restrict__ ebf,
    int* __restrict__ counts) {
#pragma clang fp contract(off)
  const int bz = blockIdx.x;
  if (bz < 8) counts[bz * 256 + threadIdx.x] = 0;
  const bool isz = bz < (N_TOK / 16);
  const int blk = isz ? bz : bz - (N_TOK / 16);
  const float* x = isz ? z : e;
  float* outs = isz ? zsum : esum;
  unsigned short* xbf = isz ? zbf : ebf;

  int wave = threadIdx.x >> 6;
  int lane = threadIdx.x & 63;
  int grp = lane >> 4, l = lane & 15;
  int row = blk * 16 + wave * 4 + grp;
  {
    const float* a = x + (size_t)row * DIM;
    float L[4];
    #pragma unroll
    for (int b = 0; b < 4; ++b) {
      const float* p = a + b * 128 + l;
      float q[8];
      #pragma unroll
      for (int j = 0; j < 8; ++j) {
        float t = p[16 * j];
        float s = t * t;
        asm volatile("" : "+v"(s));
        q[j] = s;
      }
      float v = ((q[0] + q[1]) + (q[2] + q[3])) + ((q[4] + q[5]) + (q[6] + q[7]));
      v += __shfl_xor(v, 8);
      v += __shfl_xor(v, 4);
      v += __shfl_xor(v, 2);
      v += __shfl_xor(v, 1);
      L[b] = v;
    }
    if (l == 0) outs[row] = (L[0] + L[1]) + (L[2] + L[3]);
  }
  const float* blkp = x + (size_t)blk * 16 * DIM;
  unsigned short* ob = xbf + (size_t)blk * 16 * DIM;
  #pragma unroll
  for (int u = 0; u < 4; ++u) {
    size_t off = (size_t)(u * 256 + threadIdx.x) * 8;
    float4 a2 = *(const float4*)(blkp + off);
    float4 b2 = *(const float4*)(blkp + off + 4);
    unsigned short h[8] = {f2bf(a2.x), f2bf(a2.y), f2bf(a2.z), f2bf(a2.w),
                           f2bf(b2.x), f2bf(b2.y), f2bf(b2.z), f2bf(b2.w)};
    *(uint4*)(ob + off) = *(uint4*)h;
  }
}

// Stage one 128x64-bf16 half-tile (16KB) via global_load_lds width 16.
__device__ inline void stage_half(const unsigned short* __restrict__ gsrc,
                                  unsigned short* lds, int w, int l) {
  const int swz_col = ((l & 7) ^ (l >> 3)) * 8;
  const int rsub = l >> 3;
  #pragma unroll
  for (int s4 = 0; s4 < 2; ++s4) {
    int s = w * 2 + s4;
    const unsigned short* g = gsrc + (size_t)(s * 8 + rsub) * DIM + swz_col;
    __builtin_amdgcn_global_load_lds(
        (const __attribute__((address_space(1))) unsigned int*)g,
        (__attribute__((address_space(3))) unsigned int*)(lds + s * 512),
        16, 0, 0);
  }
}

#define BAR()   asm volatile("s_barrier" ::: "memory")
#define VMCNT4  asm volatile("s_waitcnt vmcnt(4)" ::: "memory")
#define VMCNT0  asm volatile("s_waitcnt vmcnt(0)" ::: "memory")

// 8-phase MFMA GEMM — R15 structure, register epilogue (R20, validated).
// Output: ONE u32 per (token, group): bf16(groupmin)<<16 | candidate mask16.
// Mask bits remain fp32-exact (bit set iff v <= m_fp32 + EPS); only the
// group-qualification value is bf16-quantized (EPS_SEL covers 2q).
__global__ __launch_bounds__(512, 2) void gemm_groupmin(
    const unsigned short* __restrict__ ebf, const unsigned short* __restrict__ zbf,
    const float* __restrict__ esum, unsigned* __restrict__ gmv) {
  extern __shared__ unsigned short smem[];
  unsigned short* As = smem;
  unsigned short* Bs = smem + 32768;

  const int tid = threadIdx.x;
  const int tb = blockIdx.x;   // token block (128) — XCD-swizzled grid
  const int cb = blockIdx.y;   // code block (8)
  const int w = tid >> 6, l = tid & 63;
  const int lr = l & 15, lk = l >> 4;
  const int wrow = (w >> 2) * 128;
  const int wcol = (w & 3) * 64;

  f32x4 acc[8][4];
  #pragma unroll
  for (int i = 0; i < 8; ++i)
    #pragma unroll
    for (int j = 0; j < 4; ++j) acc[i][j] = (f32x4)(0.f);

  bf16x8 aR[8], bA[4], bB[4];

  const unsigned short* Ag = ebf + (size_t)(cb * 256) * DIM;
  const unsigned short* Bg = zbf + (size_t)(tb * 256) * DIM;

#define LOADA(slot, qm) do { \
  _Pragma("unroll") for (int i2 = 0; i2 < 4; ++i2) { \
    int R = wrow + (qm)*64 + i2*16 + lr; \
    int rbase = ((slot)*2 + (R>>7))*8192 + (R&127)*64; \
    aR[i2*2+0] = *(const bf16x8*)&As[rbase + (((lk    ) ^ (R&7))*8)]; \
    aR[i2*2+1] = *(const bf16x8*)&As[rbase + (((4 + lk) ^ (R&7))*8)]; \
  } } while (0)

#define LOADB(dst, slot, qn) do { \
  _Pragma("unroll") for (int j = 0; j < 2; ++j) { \
    int C = wcol + (qn)*32 + j*16 + lr; \
    int cbase = ((slot)*2 + (C>>7))*8192 + (C&127)*64; \
    dst[j*2+0] = *(const bf16x8*)&Bs[cbase + (((lk    ) ^ (C&7))*8)]; \
    dst[j*2+1] = *(const bf16x8*)&Bs[cbase + (((4 + lk) ^ (C&7))*8)]; \
  } } while (0)

#define MFMA16(qm, qn, bX) do { \
  __builtin_amdgcn_s_setprio(1); \
  _Pragma("unroll") for (int i2 = 0; i2 < 4; ++i2) \
    _Pragma("unroll") for (int j = 0; j < 2; ++j) { \
      acc[(qm)*4+i2][(qn)*2+j] = __builtin_amdgcn_mfma_f32_16x16x32_bf16( \
          aR[i2*2+0], bX[j*2+0], acc[(qm)*4+i2][(qn)*2+j], 0, 0, 0); \
      acc[(qm)*4+i2][(qn)*2+j] = __builtin_amdgcn_mfma_f32_16x16x32_bf16( \
          aR[i2*2+1], bX[j*2+1], acc[(qm)*4+i2][(qn)*2+j], 0, 0, 0); \
    } \
  __builtin_amdgcn_s_setprio(0); \
} while (0)

  stage_half(Bg,                 Bs,             w, l);
  stage_half(Bg + 128 * DIM,     Bs + 8192,      w, l);
  stage_half(Ag,                 As,             w, l);
  stage_half(Ag + 128 * DIM,     As + 8192,      w, l);
  stage_half(Bg + 64,            Bs + 2 * 8192,  w, l);
  stage_half(Bg + 128 * DIM + 64, Bs + 3 * 8192, w, l);
  VMCNT4;
  BAR();

  #pragma unroll
  for (int i = 0; i < 4; ++i) {
    const int t1k = (2 * i + 1) * 64;
    const int u0k = (2 * i + 2) * 64;
    const int u1k = (2 * i + 3) * 64;
    LOADA(0, 0); LOADB(bA, 0, 0); LOADB(bB, 0, 1);
    stage_half(Ag + t1k, As + 2 * 8192, w, l);
    BAR(); MFMA16(0, 0, bA);
    stage_half(Ag + 128 * DIM + t1k, As + 3 * 8192, w, l);
    BAR(); MFMA16(0, 1, bB);
    LOADA(0, 1);
    if (i < 3) stage_half(Bg + u0k, Bs, w, l);
    BAR(); MFMA16(1, 0, bA);
    if (i < 3) stage_half(Bg + 128 * DIM + u0k, Bs + 8192, w, l);
    BAR(); MFMA16(1, 1, bB);
    if (i < 3) { VMCNT4; } else { VMCNT0; }
    BAR();
    LOADA(1, 0); LOADB(bA, 1, 0); LOADB(bB, 1, 1);
    if (i < 3) stage_half(Ag + u0k, As, w, l);
    BAR(); MFMA16(0, 0, bA);
    if (i < 3) stage_half(Ag + 128 * DIM + u0k, As + 8192, w, l);
    BAR(); MFMA16(0, 1, bB);
    LOADA(1, 1);
    if (i < 3) stage_half(Bg + u1k, Bs + 2 * 8192, w, l);
    BAR(); MFMA16(1, 0, bA);
    if (i < 3) stage_half(Bg + 128 * DIM + u1k, Bs + 3 * 8192, w, l);
    BAR(); MFMA16(1, 1, bB);
    if (i < 3) { VMCNT4; BAR(); }
  }

  float esr[8][4];
  #pragma unroll
  for (int i = 0; i < 8; ++i)
    #pragma unroll
    for (int q = 0; q < 4; ++q)
      esr[i][q] = esum[cb * 256 + wrow + i * 16 + lk * 4 + q];

  // register-accumulated epilogue (validated R20), packed u32 output
  unsigned gmv8[4][8];
  #pragma unroll
  for (int i = 0; i < 8; ++i) {
    #pragma unroll
    for (int j = 0; j < 4; ++j) {
      float v0 = fmaf(-2.f, acc[i][j][0], esr[i][0]);
      float v1 = fmaf(-2.f, acc[i][j][1], esr[i][1]);
      float v2 = fmaf(-2.f, acc[i][j][2], esr[i][2]);
      float v3 = fmaf(-2.f, acc[i][j][3], esr[i][3]);
      float m = fminf(fminf(v0, v1), fminf(v2, v3));
      m = fminf(m, __shfl_xor(m, 16));
      m = fminf(m, __shfl_xor(m, 32));
      float gl = m + EPS;
      int mk = (((v0 <= gl) ? 1 : 0) | ((v1 <= gl) ? 2 : 0) |
                ((v2 <= gl) ? 4 : 0) | ((v3 <= gl) ? 8 : 0)) << (lk * 4);
      mk |= __shfl_xor(mk, 16);
      mk |= __shfl_xor(mk, 32);
      gmv8[j][i] = ((unsigned)f2bf(m) << 16) | (unsigned)(mk & 0xFFFF);
    }
  }
  if (lk == 0) {
    #pragma unroll
    for (int j = 0; j < 4; ++j) {
      int token = tb * 256 + wcol + j * 16 + lr;
      size_t gb = (size_t)token * 128 + cb * 16 + (w >> 2) * 8;
      uint4 q0 = {gmv8[j][0], gmv8[j][1], gmv8[j][2], gmv8[j][3]};
      uint4 q1 = {gmv8[j][4], gmv8[j][5], gmv8[j][6], gmv8[j][7]};
      *(uint4*)&gmv[gb] = q0;
      *(uint4*)&gmv[gb + 4] = q1;
    }
  }
#undef LOADA
#undef LOADB
#undef MFMA16
}

// One wave per token: mask-guided exact rescan (validated R18-R21), u32
// packed gmv. gmv lives in d_out scratch (strict ordering; z_q written by
// the separate scatter_fin kernel after all gmv reads complete).
__global__ __launch_bounds__(256) void select_exact(
    const float* __restrict__ z, const float* __restrict__ e,
    const float* __restrict__ zsum, const float* __restrict__ esum,
    const unsigned* __restrict__ gmv,
    int* __restrict__ idx_final, int* __restrict__ counts,
    float* __restrict__ out, float* __restrict__ lossp) {
  __shared__ float lred[4];
  const int wid = threadIdx.x >> 6;
  const int t = blockIdx.x * 4 + wid;
  const int lane = threadIdx.x & 63;
  const float* zr = z + (size_t)t * DIM;

  float4 za = *(const float4*)(zr + lane * 4);
  float4 zb = *(const float4*)(zr + 256 + lane * 4);

  unsigned u0 = gmv[(size_t)t * 128 + lane];
  unsigned u1 = gmv[(size_t)t * 128 + 64 + lane];
  float g0 = __uint_as_float(u0 & 0xFFFF0000u);
  float g1 = __uint_as_float(u1 & 0xFFFF0000u);
  float m = fminf(g0, g1);
  #pragma unroll
  for (int s = 32; s >= 1; s >>= 1) m = fminf(m, __shfl_xor(m, s));
  float lim = m + EPS_SEL;
  unsigned long long mm0 = __ballot(g0 <= lim);
  unsigned long long mm1 = __ballot(g1 <= lim);
  float zst = zsum[t];
  float bd = 3.402823466e38f; int bc = 0x7fffffff;

  #pragma unroll 1
  for (int half = 0; half < 2; ++half) {
    unsigned long long mk = half ? mm1 : mm0;
    while (mk) {
      int b = __ffsll((unsigned long long)mk) - 1;
      mk &= mk - 1;
      const int base = (half * 64 + b) * 16;
      unsigned gm = (unsigned)__shfl((int)(half ? u1 : u0), b) & 0xFFFFu;
      while (gm) {
        int ci = __ffs(gm) - 1;
        gm &= gm - 1;
        int c = base + ci;
        const float* er = e + (size_t)c * DIM;
        float4 ea = *(const float4*)(er + lane * 4);
        float4 eb = *(const float4*)(er + 256 + lane * 4);
        float p = 0.f;
        p = fmaf(za.x, ea.x, p); p = fmaf(za.y, ea.y, p);
        p = fmaf(za.z, ea.z, p); p = fmaf(za.w, ea.w, p);
        p = fmaf(zb.x, eb.x, p); p = fmaf(zb.y, eb.y, p);
        p = fmaf(zb.z, eb.z, p); p = fmaf(zb.w, eb.w, p);
        #pragma unroll
        for (int s = 1; s <= 32; s <<= 1) p += __shfl_xor(p, s);
        float d = (zst + esum[c]) - 2.f * p;
        if (d < bd) { bd = d; bc = c; }   // ascending c => first-index ties
      }
    }
  }
  if (lane == 0) {
    idx_final[t] = bc;
    out[IDX_OFF + t] = bfround((float)bc);
    atomicAdd(&counts[bc], 1);
    lred[wid] = bd;
  }
  __syncthreads();
  if (threadIdx.x == 0)
    lossp[blockIdx.x] = (lred[0] + lred[1]) + (lred[2] + lred[3]);
}

__device__ inline void finalize_body(const int* __restrict__ counts,
                                     const float* __restrict__ lossp,
                                     float* __restrict__ out) {
  __shared__ float red[4], red2[4];
  int tid = threadIdx.x;
  float s = 0.f;
  for (int j = tid; j < NE; j += 256) {
    float p = (float)counts[j] * (1.0f / (float)N_TOK);
    s += p * logf(p + 1e-10f);
  }
  float ls = 0.f;
  for (int j = tid; j < N_TOK / 4; j += 256) ls += lossp[j];
  #pragma unroll
  for (int m = 32; m >= 1; m >>= 1) {
    s += __shfl_xor(s, m);
    ls += __shfl_xor(ls, m);
  }
  if ((tid & 63) == 0) { red[tid >> 6] = s; red2[tid >> 6] = ls; }
  __syncthreads();
  if (tid == 0) {
    float tot = red[0] + red[1] + red[2] + red[3];
    float lt = red2[0] + red2[1] + red2[2] + red2[3];
    out[PERP_OFF] = bfround(expf(-tot));
    out[LOSS_OFF] = bfround(lt * 1.25f / (float)(N_TOK * DIM));
  }
}

// Blocks 0..4095: gather e[idx] -> bf16-rounded z_q; block 4096: finalize.
__global__ __launch_bounds__(256) void scatter_fin(
    const float* __restrict__ e, const int* __restrict__ idx_final,
    const int* __restrict__ counts, const float* __restrict__ lossp,
    float* __restrict__ out) {
  if (blockIdx.x == N_TOK / 8) { finalize_body(counts, lossp, out); return; }
  int t = blockIdx.x * 8 + (threadIdx.x >> 5);
  int g = threadIdx.x & 31;
  int idx = idx_final[t] & (NE - 1);
  const float* er = e + (size_t)idx * DIM;
  float* op = out + (size_t)t * DIM;
  #pragma unroll
  for (int p = 0; p < 4; ++p) {
    int c = p * 128 + g * 4;
    float4 ev = *(const float4*)(er + c);
    float4 ov;
    ov.x = bfround(ev.x); ov.y = bfround(ev.y);
    ov.z = bfround(ev.z); ov.w = bfround(ev.w);
    *(float4*)(op + c) = ov;
  }
}

extern "C" void kernel_launch(void* const* d_in, const int* in_sizes, int n_in,
                              void* d_out, int out_size, void* d_ws, size_t ws_size,
                              hipStream_t stream) {
  const float* z = (const float*)d_in[0];
  const float* e = (const float*)d_in[1];
  float* out = (float*)d_out;
  char* ws = (char*)d_ws;

  float*    zsum      = (float*)(ws + KB(0));      // 128 KB
  float*    esum      = (float*)(ws + KB(128));    // 8 KB
  int*      counts    = (int*)(ws + KB(136));      // 8 KB
  float*    lossp     = (float*)(ws + KB(144));    // 32 KB
  int*      idx_final = (int*)(ws + KB(176));      // 128 KB
  unsigned short* ebf = (unsigned short*)(ws + KB(304)); // 2 MB -> ends 2352 KB

  unsigned short* zbf = (unsigned short*)out;      // 32 MB scratch in d_out
  unsigned* gmv = (unsigned*)(out + 8388608);      // 16 MB scratch in d_out

  npsum_cvt_all<<<N_TOK / 16 + NE / 16, 256, 0, stream>>>(
      z, e, zsum, esum, zbf, ebf, counts);
  gemm_groupmin<<<dim3(N_TOK / 256, NE / 256), 512, 131072, stream>>>(
      ebf, zbf, esum, gmv);
  select_exact<<<N_TOK / 4, 256, 0, stream>>>(z, e, zsum, esum, gmv,
                                              idx_final, counts, out, lossp);
  scatter_fin<<<N_TOK / 8 + 1, 256, 0, stream>>>(e, idx_final, counts, lossp, out);
}